// Round 12
// baseline (72.461 us; speedup 1.0000x reference)
//
#include <hip/hip_runtime.h>
#include <hip/hip_bf16.h>

typedef float  f32x4  __attribute__((ext_vector_type(4)));
typedef short  short8 __attribute__((ext_vector_type(8)));

#define NKT 25
#define BM  64

static __device__ __forceinline__ unsigned short f2bf(float f) {
    unsigned int u = __float_as_uint(f);
    unsigned int r = (u + 0x7fffu + ((u >> 16) & 1u)) >> 16;   // RNE
    return (unsigned short)r;
}
static __device__ __forceinline__ float bf2f(unsigned short h) {
    return __uint_as_float(((unsigned int)h) << 16);
}
static __device__ __forceinline__ short8 cvt8(f32x4 a, f32x4 b) {
    __hip_bfloat162 p0 = __float22bfloat162_rn(make_float2(a[0], a[1]));
    __hip_bfloat162 p1 = __float22bfloat162_rn(make_float2(a[2], a[3]));
    __hip_bfloat162 p2 = __float22bfloat162_rn(make_float2(b[0], b[1]));
    __hip_bfloat162 p3 = __float22bfloat162_rn(make_float2(b[2], b[3]));
    short8 r;
    reinterpret_cast<unsigned int*>(&r)[0] = *reinterpret_cast<unsigned int*>(&p0);
    reinterpret_cast<unsigned int*>(&r)[1] = *reinterpret_cast<unsigned int*>(&p1);
    reinterpret_cast<unsigned int*>(&r)[2] = *reinterpret_cast<unsigned int*>(&p2);
    reinterpret_cast<unsigned int*>(&r)[3] = *reinterpret_cast<unsigned int*>(&p3);
    return r;
}

// W_eff = fc1_w o ConvMatrix, layout [kt(25)][j(8)][kc(4)][r16(16)][8] bf16
// so a j-group B-load is one dense 1KB line: elem idx =
// kt*4096 + j*512 + kc*128 + r16*8 + e, with col = j*16+r16, p = kt*32+kc*8+e.
// fc2 bf16 at ws[102400..103679].
__global__ __launch_bounds__(256) void weff_prep(
    const float* __restrict__ fc1_w,    // [128][676]
    const float* __restrict__ conv_w,   // [3][3]
    const float* __restrict__ fc2_w,    // [10][128]
    unsigned short* __restrict__ ws)
{
    int idx = blockIdx.x * 256 + threadIdx.x;   // o*800 + p
    if (idx >= 128 * 800) return;
    if (idx < 1280) ws[102400 + idx] = f2bf(fc2_w[idx]);
    int o = idx / 800, p = idx - o * 800;
    float s = 0.f;
    if (p < 784) {
        int y = p / 28, xx = p - y * 28;
        #pragma unroll
        for (int dr = 0; dr < 3; ++dr) {
            int r = y - dr;
            if (r < 0 || r > 25) continue;
            #pragma unroll
            for (int dc = 0; dc < 3; ++dc) {
                int c = xx - dc;
                if (c < 0 || c > 25) continue;
                s += fc1_w[o * 676 + r * 26 + c] * conv_w[dr * 3 + dc];
            }
        }
    }
    ws[(p >> 5) * 4096 + (o >> 4) * 512 + ((p >> 3) & 3) * 128
       + (o & 15) * 8 + (p & 7)] = f2bf(s);
}

// Fused: H = relu(X @ Weff^T + b1); out = H @ fc2^T + b2
// Wave-private, BARRIER-FREE K-loop: each wave owns 16 rows x 128 cols.
// A: fp32 gload_lds into 4 private slots (XOR-granule swizzle, bank-
// balanced); B: global->reg 2-deep, dense 1KB loads. Whole grid resident
// (1024 blk x 256 thr = 4 blk/CU). Only 2 __syncthreads (epilogue).
__global__ __launch_bounds__(256, 4) void fused_fwd(
    const float* __restrict__ x,              // [B][784]
    const unsigned short* __restrict__ weff,  // see layout above (+fc2wb)
    const float* __restrict__ fc1_b,          // [128]
    const float* __restrict__ fc2_b,          // [10]
    float* __restrict__ out,                  // [B][10]
    int B)
{
    __shared__ __align__(16) char pool[32768];  // [wid][slot4][2048B]; Hs overlays

    const int tid  = threadIdx.x;
    const int lane = tid & 63;
    const int wid  = tid >> 6;                // 0..3: 16-row band per wave
    const int r16  = lane & 15;
    const int kc   = lane >> 4;               // 0..3
    const int m0   = blockIdx.x * BM;
    const unsigned short* fc2wb = weff + 102400;

    // ---- A staging: wave-private. Instr q covers LDS granule G=q*64+lane:
    // row_local = G>>3 (= q*8 + lane>>3), s = G&7; slot(row,s) holds source
    // granule u = s ^ (row&7). Note (8+l)&7 == l&7 -> same u for both instrs.
    const int srow = lane >> 3;               // 0..7
    const int su   = ((lane & 7) ^ (srow & 7)) * 4;   // float offset in 32-k
    int gr = m0 + wid * 16 + srow; if (gr >= B) gr = B - 1;
    int gr2 = gr + 8; if (gr2 >= B) gr2 = B - 1;
    const float* xa0 = x + (size_t)gr  * 784;
    const float* xa1 = x + (size_t)gr2 * 784;

#define STAGE_A(slot_, kt_) do {                                              \
        int k_ = (kt_) * 32 + su; if (k_ > 780) k_ = 0;                       \
        char* d_ = pool + wid * 8192 + (slot_) * 2048 + lane * 16;            \
        __builtin_amdgcn_global_load_lds(                                     \
            (const __attribute__((address_space(1))) void*)(xa0 + k_),        \
            (__attribute__((address_space(3))) void*)d_, 16, 0, 0);           \
        __builtin_amdgcn_global_load_lds(                                     \
            (const __attribute__((address_space(1))) void*)(xa1 + k_),        \
            (__attribute__((address_space(3))) void*)(d_ + 1024), 16, 0, 0);  \
    } while (0)

    // ---- B: 8 dense 1KB loads per step into 2-deep register rotation
    const unsigned short* wb = weff + lane * 8;   // + kt*4096 + j*512
    short8 breg[2][8];
#define LOADB(set_, kt_) do {                                                 \
        const unsigned short* p_ = wb + (size_t)(kt_) * 4096;                 \
        breg[set_][0] = *reinterpret_cast<const short8*>(p_);                 \
        breg[set_][1] = *reinterpret_cast<const short8*>(p_ + 512);           \
        breg[set_][2] = *reinterpret_cast<const short8*>(p_ + 1024);          \
        breg[set_][3] = *reinterpret_cast<const short8*>(p_ + 1536);          \
        breg[set_][4] = *reinterpret_cast<const short8*>(p_ + 2048);          \
        breg[set_][5] = *reinterpret_cast<const short8*>(p_ + 2560);          \
        breg[set_][6] = *reinterpret_cast<const short8*>(p_ + 3072);          \
        breg[set_][7] = *reinterpret_cast<const short8*>(p_ + 3584);          \
    } while (0)

    // ---- A-frag read offsets: want granules {2kc, 2kc+1} of row r16 ->
    // slots (2kc)^(r16&7), (2kc+1)^(r16&7). Balanced: 8 lanes/bank-group.
    const int aoff0 = wid * 8192 + r16 * 128 + (((2 * kc)    ) ^ (r16 & 7)) * 16;
    const int aoff1 = wid * 8192 + r16 * 128 + (((2 * kc) | 1) ^ (r16 & 7)) * 16;

    f32x4 acc[8];
    #pragma unroll
    for (int j = 0; j < 8; ++j) acc[j] = (f32x4)(0.f);

    asm volatile("s_waitcnt vmcnt(0)" ::: "memory");   // clean FIFO

    // ---- prologue: FIFO = [A0(2), A1(2), A2(2), B0(8)] ----
    STAGE_A(0, 0); STAGE_A(1, 1); STAGE_A(2, 2);
    LOADB(0, 0);

    // Per-step FIFO (LOADB before STAGE_A): step i issues [B(i+1)8, A(i+3)2].
    // younger-than-A(i): i=0:12  i=1:20  i=2:28  i>=3:20.
    #pragma unroll
    for (int i = 0; i < NKT; ++i) {
        if (i == 0)      asm volatile("s_waitcnt vmcnt(12)" ::: "memory");
        else if (i == 1) asm volatile("s_waitcnt vmcnt(20)" ::: "memory");
        else if (i == 2) asm volatile("s_waitcnt vmcnt(28)" ::: "memory");
        else             asm volatile("s_waitcnt vmcnt(20)" ::: "memory");
        __builtin_amdgcn_sched_barrier(0);

        f32x4 a0 = *reinterpret_cast<const f32x4*>(pool + (i & 3) * 2048 + aoff0);
        f32x4 a1 = *reinterpret_cast<const f32x4*>(pool + (i & 3) * 2048 + aoff1);
        __builtin_amdgcn_sched_barrier(0);

        const int kb = (i + 1 <= 24) ? (i + 1) : 24;
        LOADB((i + 1) & 1, kb);                // B first (keeps A pipeline alive
        __builtin_amdgcn_sched_barrier(0);     //  under compiler pre-MFMA waits)
        const int ka = (i + 3 <= 24) ? (i + 3) : 24;
        STAGE_A((i + 3) & 3, ka);
        __builtin_amdgcn_sched_barrier(0);

        short8 af = cvt8(a0, a1);
        acc[0] = __builtin_amdgcn_mfma_f32_16x16x32_bf16(af, breg[i & 1][0], acc[0], 0, 0, 0);
        acc[1] = __builtin_amdgcn_mfma_f32_16x16x32_bf16(af, breg[i & 1][1], acc[1], 0, 0, 0);
        acc[2] = __builtin_amdgcn_mfma_f32_16x16x32_bf16(af, breg[i & 1][2], acc[2], 0, 0, 0);
        acc[3] = __builtin_amdgcn_mfma_f32_16x16x32_bf16(af, breg[i & 1][3], acc[3], 0, 0, 0);
        acc[4] = __builtin_amdgcn_mfma_f32_16x16x32_bf16(af, breg[i & 1][4], acc[4], 0, 0, 0);
        acc[5] = __builtin_amdgcn_mfma_f32_16x16x32_bf16(af, breg[i & 1][5], acc[5], 0, 0, 0);
        acc[6] = __builtin_amdgcn_mfma_f32_16x16x32_bf16(af, breg[i & 1][6], acc[6], 0, 0, 0);
        acc[7] = __builtin_amdgcn_mfma_f32_16x16x32_bf16(af, breg[i & 1][7], acc[7], 0, 0, 0);
    }
#undef STAGE_A
#undef LOADB

    // drain dummy tail gloads before overlaying the pool
    asm volatile("s_waitcnt vmcnt(0) lgkmcnt(0)" ::: "memory");
    __syncthreads();

    // ---- epilogue: bias + ReLU -> Hs (bf16), overlays pool ----
    unsigned short (*Hs)[136] = (unsigned short (*)[136])pool;
    #pragma unroll
    for (int j = 0; j < 8; ++j) {
        int ncol = j * 16 + r16;
        float bias = fc1_b[ncol];
        #pragma unroll
        for (int r = 0; r < 4; ++r) {
            int mrow = wid * 16 + kc * 4 + r;
            float h = acc[j][r] + bias;
            Hs[mrow][ncol] = f2bf(h > 0.f ? h : 0.f);
        }
    }
    __syncthreads();

    // ---- stage 2: out[64][10] = Hs @ fc2^T + b2 (fc2 bf16 from L1) ----
    #pragma unroll
    for (int it = 0; it < 3; ++it) {
        int idx = it * 256 + tid;              // 0..767, valid < 640
        if (idx < BM * 10) {
            int row = idx / 10, j = idx - row * 10;
            if ((m0 + row) < B) {
                float sum = fc2_b[j];
                const unsigned short* wrow = fc2wb + j * 128;
                #pragma unroll
                for (int n8 = 0; n8 < 16; ++n8) {
                    short8 h = *reinterpret_cast<const short8*>(&Hs[row][n8 * 8]);
                    short8 w = *reinterpret_cast<const short8*>(wrow + n8 * 8);
                    #pragma unroll
                    for (int k2 = 0; k2 < 8; ++k2)
                        sum += bf2f(((unsigned short*)&h)[k2]) *
                               bf2f(((unsigned short*)&w)[k2]);
                }
                out[(size_t)(m0 + row) * 10 + j] = sum;
            }
        }
    }
}

extern "C" void kernel_launch(void* const* d_in, const int* in_sizes, int n_in,
                              void* d_out, int out_size, void* d_ws, size_t ws_size,
                              hipStream_t stream) {
    const float* x      = (const float*)d_in[0];
    const float* conv_w = (const float*)d_in[1];
    const float* fc1_w  = (const float*)d_in[2];
    const float* fc1_b  = (const float*)d_in[3];
    const float* fc2_w  = (const float*)d_in[4];
    const float* fc2_b  = (const float*)d_in[5];
    float* out = (float*)d_out;
    unsigned short* ws = (unsigned short*)d_ws;   // 103680 bf16 = 207360 B

    int B = in_sizes[0] / 784;

    weff_prep<<<(128 * 800 + 255) / 256, 256, 0, stream>>>(fc1_w, conv_w, fc2_w, ws);

    int nblk = (B + BM - 1) / BM;
    fused_fwd<<<nblk, 256, 0, stream>>>(x, ws, fc1_b, fc2_b, out, B);
}